// Round 4
// baseline (3261.113 us; speedup 1.0000x reference)
//
#include <hip/hip_runtime.h>

// Problem constants (fixed by setup_inputs)
constexpr int Bb = 8, Nn = 1024, Cc = 768, Hh = 12, Dd = 64;
constexpr int Mtot = Bb * Nn;          // 8192
constexpr int QKVN = 3 * Cc;           // 2304
constexpr int BH = Bb * Hh;            // 96

// ---------------------------------------------------------------------------
// Kernel 1: QKV GEMM  x[8192,768] @ w_qkv[768,2304] -> q/k/v [96][1024][64]
// ---------------------------------------------------------------------------
__global__ __launch_bounds__(256)
void gemm_qkv(const float* __restrict__ A, const float* __restrict__ Bw,
              float* __restrict__ qkv_ws) {
  constexpr int BM = 128, BN = 128, BK = 16;
  __shared__ float As[BK][BM + 4];
  __shared__ float Bs[BK][BN];

  const int bn = blockIdx.x;
  const int bm = blockIdx.y;
  const int tid = threadIdx.x;
  const int tr = tid >> 4;
  const int tc = tid & 15;
  const int m0 = bm * BM, n0 = bn * BN;

  float acc[8][8] = {};

  for (int k0 = 0; k0 < Cc; k0 += BK) {
    #pragma unroll
    for (int s = 0; s < 2; ++s) {
      int f4 = tid + s * 256;
      int row = f4 >> 2;
      int c4 = (f4 & 3) * 4;
      float4 av = *(const float4*)&A[(size_t)(m0 + row) * Cc + k0 + c4];
      As[c4 + 0][row] = av.x;
      As[c4 + 1][row] = av.y;
      As[c4 + 2][row] = av.z;
      As[c4 + 3][row] = av.w;
    }
    #pragma unroll
    for (int s = 0; s < 2; ++s) {
      int f4 = tid + s * 256;
      int row = f4 >> 5;
      int c4 = (f4 & 31) * 4;
      *(float4*)&Bs[row][c4] =
          *(const float4*)&Bw[(size_t)(k0 + row) * QKVN + n0 + c4];
    }
    __syncthreads();

    #pragma unroll
    for (int k = 0; k < BK; ++k) {
      float a[8], bb[8];
      *(float4*)&a[0] = *(const float4*)&As[k][tr * 8];
      *(float4*)&a[4] = *(const float4*)&As[k][tr * 8 + 4];
      *(float4*)&bb[0] = *(const float4*)&Bs[k][tc * 8];
      *(float4*)&bb[4] = *(const float4*)&Bs[k][tc * 8 + 4];
      #pragma unroll
      for (int i = 0; i < 8; ++i)
        #pragma unroll
        for (int j = 0; j < 8; ++j)
          acc[i][j] = fmaf(a[i], bb[j], acc[i][j]);
    }
    __syncthreads();
  }

  const int t = n0 / Cc;
  #pragma unroll
  for (int i = 0; i < 8; ++i) {
    int m = m0 + tr * 8 + i;
    int bIdx = m >> 10;
    int nIdx = m & 1023;
    #pragma unroll
    for (int j = 0; j < 8; ++j) {
      int e = n0 + tc * 8 + j;
      int rem = e - t * Cc;
      int h = rem >> 6;
      int d = rem & 63;
      qkv_ws[(((size_t)t * BH + bIdx * Hh + h) * Nn + nIdx) * Dd + d] = acc[i][j];
    }
  }
}

// ---------------------------------------------------------------------------
// Kernel 2: attention, KV-split-4.
// Block = 256 threads = 4 waves. All 4 waves own the SAME 64 q-rows
// (lane = row); wave w sweeps KV rows [w*256,(w+1)*256) with lane-local
// online softmax. 3-round sequential merge via one LDS buffer.
// Waves: 1536 blocks x 4 = 6144 (24/CU) vs 1536 (6/CU) before.
// ---------------------------------------------------------------------------
__global__ __launch_bounds__(256)
void attn(const float* __restrict__ qkv_ws, float* __restrict__ aout) {
  const int blk = blockIdx.x;           // 0..1535
  const int bh = blk >> 4;
  const int rt = blk & 15;
  const int tid = threadIdx.x;
  const int w = tid >> 6;               // 0..3
  const int lane = tid & 63;
  const int row = rt * 64 + lane;
  const int b = bh / Hh, h = bh % Hh;

  __shared__ float buf_o[64][68];       // +4 pad: spread banks for float4 rows
  __shared__ float buf_m[64];
  __shared__ float buf_l[64];

  const float* qp = qkv_ws + ((size_t)bh * Nn + row) * Dd;
  const float4* kbase = (const float4*)(qkv_ws + ((size_t)(BH + bh) * Nn) * Dd);
  const float4* vbase = (const float4*)(qkv_ws + ((size_t)(2 * BH + bh) * Nn) * Dd);

  float q[64];
  #pragma unroll
  for (int d4 = 0; d4 < 16; ++d4) {
    float4 t4 = ((const float4*)qp)[d4];
    q[d4 * 4 + 0] = t4.x; q[d4 * 4 + 1] = t4.y;
    q[d4 * 4 + 2] = t4.z; q[d4 * 4 + 3] = t4.w;
  }

  float o[64] = {};
  float mrun = -1e30f, l = 0.f;
  const float scale = 0.125f;

  const int j0 = w * (Nn / 4), j1 = j0 + (Nn / 4);
  for (int jt = j0; jt < j1; jt += 8) {
    float s[8];
    #pragma unroll
    for (int jj = 0; jj < 8; ++jj) {
      const float4* kr = kbase + (size_t)(jt + jj) * 16;
      float acc = 0.f;
      #pragma unroll
      for (int d4 = 0; d4 < 16; ++d4) {
        float4 kv = kr[d4];
        acc = fmaf(q[d4 * 4 + 0], kv.x, acc);
        acc = fmaf(q[d4 * 4 + 1], kv.y, acc);
        acc = fmaf(q[d4 * 4 + 2], kv.z, acc);
        acc = fmaf(q[d4 * 4 + 3], kv.w, acc);
      }
      s[jj] = acc * scale;
    }
    float tmax = s[0];
    #pragma unroll
    for (int jj = 1; jj < 8; ++jj) tmax = fmaxf(tmax, s[jj]);
    float mn = fmaxf(mrun, tmax);
    float corr = __expf(mrun - mn);
    l *= corr;
    #pragma unroll
    for (int d = 0; d < 64; ++d) o[d] *= corr;
    #pragma unroll
    for (int jj = 0; jj < 8; ++jj) {
      float p = __expf(s[jj] - mn);
      l += p;
      const float4* vr = vbase + (size_t)(jt + jj) * 16;
      #pragma unroll
      for (int d4 = 0; d4 < 16; ++d4) {
        float4 vv = vr[d4];
        o[d4 * 4 + 0] = fmaf(p, vv.x, o[d4 * 4 + 0]);
        o[d4 * 4 + 1] = fmaf(p, vv.y, o[d4 * 4 + 1]);
        o[d4 * 4 + 2] = fmaf(p, vv.z, o[d4 * 4 + 2]);
        o[d4 * 4 + 3] = fmaf(p, vv.w, o[d4 * 4 + 3]);
      }
    }
    mrun = mn;
  }

  // ---- cross-wave merge: (m,l,o) over w=0..3, single LDS buffer ----
  // Round A: w1 -> buf; w0 merges.  Round B: w3 -> buf; w2 merges.
  // Round C: w2 -> buf; w0 merges + writes output.
  #define WRITE_BUF()                                            \
    do {                                                         \
      _Pragma("unroll")                                          \
      for (int d4 = 0; d4 < 16; ++d4) {                          \
        float4 t4;                                               \
        t4.x = o[d4 * 4 + 0]; t4.y = o[d4 * 4 + 1];              \
        t4.z = o[d4 * 4 + 2]; t4.w = o[d4 * 4 + 3];              \
        *(float4*)&buf_o[lane][d4 * 4] = t4;                     \
      }                                                          \
      buf_m[lane] = mrun; buf_l[lane] = l;                       \
    } while (0)

  #define MERGE_BUF()                                            \
    do {                                                         \
      float m2 = buf_m[lane], l2 = buf_l[lane];                  \
      float mn2 = fmaxf(mrun, m2);                               \
      float c1 = __expf(mrun - mn2), c2 = __expf(m2 - mn2);      \
      l = l * c1 + l2 * c2;                                      \
      _Pragma("unroll")                                          \
      for (int d4 = 0; d4 < 16; ++d4) {                          \
        float4 t4 = *(const float4*)&buf_o[lane][d4 * 4];        \
        o[d4 * 4 + 0] = o[d4 * 4 + 0] * c1 + t4.x * c2;          \
        o[d4 * 4 + 1] = o[d4 * 4 + 1] * c1 + t4.y * c2;          \
        o[d4 * 4 + 2] = o[d4 * 4 + 2] * c1 + t4.z * c2;          \
        o[d4 * 4 + 3] = o[d4 * 4 + 3] * c1 + t4.w * c2;          \
      }                                                          \
      mrun = mn2;                                                \
    } while (0)

  __syncthreads();
  if (w == 1) WRITE_BUF();
  __syncthreads();
  if (w == 0) MERGE_BUF();
  __syncthreads();
  if (w == 3) WRITE_BUF();
  __syncthreads();
  if (w == 2) MERGE_BUF();
  __syncthreads();
  if (w == 2) WRITE_BUF();
  __syncthreads();
  if (w == 0) {
    MERGE_BUF();
    const float inv = 1.0f / l;
    float* op = aout + ((size_t)(b * Nn + row)) * Cc + h * Dd;
    #pragma unroll
    for (int d4 = 0; d4 < 16; ++d4) {
      float4 r;
      r.x = o[d4 * 4 + 0] * inv; r.y = o[d4 * 4 + 1] * inv;
      r.z = o[d4 * 4 + 2] * inv; r.w = o[d4 * 4 + 3] * inv;
      *(float4*)&op[d4 * 4] = r;
    }
  }
  #undef WRITE_BUF
  #undef MERGE_BUF
}

// ---------------------------------------------------------------------------
// Kernel 3: proj GEMM  aout[8192,768] @ w_proj[768,768] + b_proj -> out
// ---------------------------------------------------------------------------
__global__ __launch_bounds__(256)
void gemm_proj(const float* __restrict__ A, const float* __restrict__ Bw,
               const float* __restrict__ bias, float* __restrict__ out) {
  constexpr int BM = 128, BN = 128, BK = 16;
  __shared__ float As[BK][BM + 4];
  __shared__ float Bs[BK][BN];

  const int bn = blockIdx.x;
  const int bm = blockIdx.y;
  const int tid = threadIdx.x;
  const int tr = tid >> 4, tc = tid & 15;
  const int m0 = bm * BM, n0 = bn * BN;

  float acc[8][8] = {};

  for (int k0 = 0; k0 < Cc; k0 += BK) {
    #pragma unroll
    for (int s = 0; s < 2; ++s) {
      int f4 = tid + s * 256;
      int row = f4 >> 2;
      int c4 = (f4 & 3) * 4;
      float4 av = *(const float4*)&A[(size_t)(m0 + row) * Cc + k0 + c4];
      As[c4 + 0][row] = av.x;
      As[c4 + 1][row] = av.y;
      As[c4 + 2][row] = av.z;
      As[c4 + 3][row] = av.w;
    }
    #pragma unroll
    for (int s = 0; s < 2; ++s) {
      int f4 = tid + s * 256;
      int row = f4 >> 5;
      int c4 = (f4 & 31) * 4;
      *(float4*)&Bs[row][c4] =
          *(const float4*)&Bw[(size_t)(k0 + row) * Cc + n0 + c4];
    }
    __syncthreads();

    #pragma unroll
    for (int k = 0; k < BK; ++k) {
      float a[8], bb[8];
      *(float4*)&a[0] = *(const float4*)&As[k][tr * 8];
      *(float4*)&a[4] = *(const float4*)&As[k][tr * 8 + 4];
      *(float4*)&bb[0] = *(const float4*)&Bs[k][tc * 8];
      *(float4*)&bb[4] = *(const float4*)&Bs[k][tc * 8 + 4];
      #pragma unroll
      for (int i = 0; i < 8; ++i)
        #pragma unroll
        for (int j = 0; j < 8; ++j)
          acc[i][j] = fmaf(a[i], bb[j], acc[i][j]);
    }
    __syncthreads();
  }

  float bv[8];
  #pragma unroll
  for (int j = 0; j < 8; ++j) bv[j] = bias[n0 + tc * 8 + j];

  #pragma unroll
  for (int i = 0; i < 8; ++i) {
    int m = m0 + tr * 8 + i;
    float4 r0, r1;
    r0.x = acc[i][0] + bv[0]; r0.y = acc[i][1] + bv[1];
    r0.z = acc[i][2] + bv[2]; r0.w = acc[i][3] + bv[3];
    r1.x = acc[i][4] + bv[4]; r1.y = acc[i][5] + bv[5];
    r1.z = acc[i][6] + bv[6]; r1.w = acc[i][7] + bv[7];
    *(float4*)&out[(size_t)m * Cc + n0 + tc * 8] = r0;
    *(float4*)&out[(size_t)m * Cc + n0 + tc * 8 + 4] = r1;
  }
}

// ---------------------------------------------------------------------------
extern "C" void kernel_launch(void* const* d_in, const int* in_sizes, int n_in,
                              void* d_out, int out_size, void* d_ws, size_t ws_size,
                              hipStream_t stream) {
  const float* x      = (const float*)d_in[0];
  const float* w_qkv  = (const float*)d_in[1];
  const float* w_proj = (const float*)d_in[2];
  const float* b_proj = (const float*)d_in[3];
  float* out = (float*)d_out;

  float* qkvws = (float*)d_ws;                               // 3*96*1024*64 f32
  float* aout  = qkvws + (size_t)3 * BH * Nn * Dd;           // 8192*768 f32

  dim3 g1(QKVN / 128, Mtot / 128);
  gemm_qkv<<<g1, 256, 0, stream>>>(x, w_qkv, qkvws);

  attn<<<BH * (Nn / 64), 256, 0, stream>>>(qkvws, aout);

  dim3 g3(Cc / 128, Mtot / 128);
  gemm_proj<<<g3, 256, 0, stream>>>(aout, w_proj, b_proj, out);
}

// Round 5
// 964.981 us; speedup vs baseline: 3.3795x; 3.3795x over previous
//
#include <hip/hip_runtime.h>

// Problem constants (fixed by setup_inputs)
constexpr int Bb = 8, Nn = 1024, Cc = 768, Hh = 12, Dd = 64;
constexpr int Mtot = Bb * Nn;          // 8192
constexpr int QKVN = 3 * Cc;           // 2304
constexpr int BH = Bb * Hh;            // 96

// ---------------------------------------------------------------------------
// Kernel 1: QKV GEMM  x[8192,768] @ w_qkv[768,2304] -> q/k/v [96][1024][64]
// (verified R2 version, unchanged)
// ---------------------------------------------------------------------------
__global__ __launch_bounds__(256)
void gemm_qkv(const float* __restrict__ A, const float* __restrict__ Bw,
              float* __restrict__ qkv_ws) {
  constexpr int BM = 128, BN = 128, BK = 16;
  __shared__ float As[BK][BM + 4];
  __shared__ float Bs[BK][BN];

  const int bn = blockIdx.x;
  const int bm = blockIdx.y;
  const int tid = threadIdx.x;
  const int tr = tid >> 4;
  const int tc = tid & 15;
  const int m0 = bm * BM, n0 = bn * BN;

  float acc[8][8] = {};

  for (int k0 = 0; k0 < Cc; k0 += BK) {
    #pragma unroll
    for (int s = 0; s < 2; ++s) {
      int f4 = tid + s * 256;
      int row = f4 >> 2;
      int c4 = (f4 & 3) * 4;
      float4 av = *(const float4*)&A[(size_t)(m0 + row) * Cc + k0 + c4];
      As[c4 + 0][row] = av.x;
      As[c4 + 1][row] = av.y;
      As[c4 + 2][row] = av.z;
      As[c4 + 3][row] = av.w;
    }
    #pragma unroll
    for (int s = 0; s < 2; ++s) {
      int f4 = tid + s * 256;
      int row = f4 >> 5;
      int c4 = (f4 & 31) * 4;
      *(float4*)&Bs[row][c4] =
          *(const float4*)&Bw[(size_t)(k0 + row) * QKVN + n0 + c4];
    }
    __syncthreads();

    #pragma unroll
    for (int k = 0; k < BK; ++k) {
      float a[8], bb[8];
      *(float4*)&a[0] = *(const float4*)&As[k][tr * 8];
      *(float4*)&a[4] = *(const float4*)&As[k][tr * 8 + 4];
      *(float4*)&bb[0] = *(const float4*)&Bs[k][tc * 8];
      *(float4*)&bb[4] = *(const float4*)&Bs[k][tc * 8 + 4];
      #pragma unroll
      for (int i = 0; i < 8; ++i)
        #pragma unroll
        for (int j = 0; j < 8; ++j)
          acc[i][j] = fmaf(a[i], bb[j], acc[i][j]);
    }
    __syncthreads();
  }

  const int t = n0 / Cc;
  #pragma unroll
  for (int i = 0; i < 8; ++i) {
    int m = m0 + tr * 8 + i;
    int bIdx = m >> 10;
    int nIdx = m & 1023;
    #pragma unroll
    for (int j = 0; j < 8; ++j) {
      int e = n0 + tc * 8 + j;
      int rem = e - t * Cc;
      int h = rem >> 6;
      int d = rem & 63;
      qkv_ws[(((size_t)t * BH + bIdx * Hh + h) * Nn + nIdx) * Dd + d] = acc[i][j];
    }
  }
}

// ---------------------------------------------------------------------------
// Kernel 2: attention as two LDS-tiled GEMMs per KV tile (flash-style).
// Block = 256 thr (16x16 grid, 4x4 microtile), one 64-row q-tile per block.
// LDS: Qs^T | KPs (K^T, then aliased as P^T) | Vs  = 52 KB -> 3 blocks/CU.
// Staging loads are per-lane coalesced (1 KB contiguous per wave).
// ---------------------------------------------------------------------------
__global__ __launch_bounds__(256)
void attn(const float* __restrict__ qkv_ws, float* __restrict__ aout) {
  constexpr int LDW = 68;                 // LDS row stride (words), 16B-aligned
  __shared__ float Qs[64][LDW];           // Qs[k][r]  = Q[r][k]
  __shared__ float KPs[64][LDW];          // phase1: KPs[k][c] = K[c][k]; phase2: KPs[c][r] = P[r][c]
  __shared__ float Vs[64][LDW];           // Vs[c][d]

  const int bid = blockIdx.x;             // 0..1535, bh-major for L2 locality
  const int bh = bid >> 4;
  const int qt = bid & 15;
  const int b = bh / Hh, h = bh % Hh;
  const int tid = threadIdx.x;
  const int tr = tid >> 4;                // 0..15  (q-row group)
  const int tc = tid & 15;                // 0..15  (col group)

  const float* Qg = qkv_ws + ((size_t)bh * Nn + qt * 64) * Dd;
  const float* Kg = qkv_ws + ((size_t)(BH + bh) * Nn) * Dd;
  const float* Vg = qkv_ws + ((size_t)(2 * BH + bh) * Nn) * Dd;

  // Stage Q transposed (once). f4-linear == contiguous memory -> coalesced.
  #pragma unroll
  for (int s = 0; s < 4; ++s) {
    int f4 = s * 256 + tid;               // 0..1023
    int row = f4 >> 4;                    // 0..63
    int c4 = (f4 & 15) * 4;               // 0..60
    float4 v = *(const float4*)&Qg[row * 64 + c4];
    Qs[c4 + 0][row] = v.x; Qs[c4 + 1][row] = v.y;
    Qs[c4 + 2][row] = v.z; Qs[c4 + 3][row] = v.w;
  }

  float o[4][4] = {};
  float mrow[4] = {-1e30f, -1e30f, -1e30f, -1e30f};
  float lrow[4] = {};
  const float scale = 0.125f;             // 64^-0.5

  for (int kt = 0; kt < 16; ++kt) {
    __syncthreads();                      // prev PV GEMM readers done
    // Stage K^T -> KPs, V -> Vs (both coalesced from global)
    #pragma unroll
    for (int s = 0; s < 4; ++s) {
      int f4 = s * 256 + tid;
      int row = f4 >> 4;
      int c4 = (f4 & 15) * 4;
      float4 kv4 = *(const float4*)&Kg[(size_t)(kt * 64 + row) * 64 + c4];
      KPs[c4 + 0][row] = kv4.x; KPs[c4 + 1][row] = kv4.y;
      KPs[c4 + 2][row] = kv4.z; KPs[c4 + 3][row] = kv4.w;
      float4 vv4 = *(const float4*)&Vg[(size_t)(kt * 64 + row) * 64 + c4];
      *(float4*)&Vs[row][c4] = vv4;
    }
    __syncthreads();

    // S GEMM: sv[i][j] = sum_k Q[tr4+i][k] * K[tc4+j][k]
    float sv[4][4] = {};
    #pragma unroll 4
    for (int k = 0; k < 64; ++k) {
      float a[4], bb[4];
      *(float4*)&a[0]  = *(const float4*)&Qs[k][tr * 4];
      *(float4*)&bb[0] = *(const float4*)&KPs[k][tc * 4];
      #pragma unroll
      for (int i = 0; i < 4; ++i)
        #pragma unroll
        for (int j = 0; j < 4; ++j)
          sv[i][j] = fmaf(a[i], bb[j], sv[i][j]);
    }

    // Online softmax (registers + shfl over the 16-lane tc group)
    float p[4][4];
    #pragma unroll
    for (int i = 0; i < 4; ++i) {
      #pragma unroll
      for (int j = 0; j < 4; ++j) sv[i][j] *= scale;
      float t0 = fmaxf(fmaxf(sv[i][0], sv[i][1]), fmaxf(sv[i][2], sv[i][3]));
      #pragma unroll
      for (int m = 1; m < 16; m <<= 1) t0 = fmaxf(t0, __shfl_xor(t0, m));
      float mn = fmaxf(mrow[i], t0);
      float corr = __expf(mrow[i] - mn);
      mrow[i] = mn;
      lrow[i] *= corr;
      #pragma unroll
      for (int j = 0; j < 4; ++j) o[i][j] *= corr;
      float s0 = 0.f;
      #pragma unroll
      for (int j = 0; j < 4; ++j) {
        p[i][j] = __expf(sv[i][j] - mn);
        s0 += p[i][j];
      }
      #pragma unroll
      for (int m = 1; m < 16; m <<= 1) s0 += __shfl_xor(s0, m);
      lrow[i] += s0;
    }

    __syncthreads();                      // all waves done reading KPs (K^T)
    // Write P^T into KPs: KPs[c][r] = P[r][c]
    #pragma unroll
    for (int j = 0; j < 4; ++j) {
      float4 pc;
      pc.x = p[0][j]; pc.y = p[1][j]; pc.z = p[2][j]; pc.w = p[3][j];
      *(float4*)&KPs[tc * 4 + j][tr * 4] = pc;
    }
    __syncthreads();

    // PV GEMM: o[i][j] += sum_c P[tr4+i][c] * V[c][tc4+j]
    #pragma unroll 4
    for (int c = 0; c < 64; ++c) {
      float a[4], bb[4];
      *(float4*)&a[0]  = *(const float4*)&KPs[c][tr * 4];
      *(float4*)&bb[0] = *(const float4*)&Vs[c][tc * 4];
      #pragma unroll
      for (int i = 0; i < 4; ++i)
        #pragma unroll
        for (int j = 0; j < 4; ++j)
          o[i][j] = fmaf(a[i], bb[j], o[i][j]);
    }
  }

  // Epilogue: O /= l, write [b, n, h*64+d]
  #pragma unroll
  for (int i = 0; i < 4; ++i) {
    float inv = 1.0f / lrow[i];
    float4 r;
    r.x = o[i][0] * inv; r.y = o[i][1] * inv;
    r.z = o[i][2] * inv; r.w = o[i][3] * inv;
    *(float4*)&aout[((size_t)(b * Nn + qt * 64 + tr * 4 + i)) * Cc + h * 64 + tc * 4] = r;
  }
}

// ---------------------------------------------------------------------------
// Kernel 3: proj GEMM  aout[8192,768] @ w_proj[768,768] + b_proj -> out
// (verified R2 version, unchanged)
// ---------------------------------------------------------------------------
__global__ __launch_bounds__(256)
void gemm_proj(const float* __restrict__ A, const float* __restrict__ Bw,
               const float* __restrict__ bias, float* __restrict__ out) {
  constexpr int BM = 128, BN = 128, BK = 16;
  __shared__ float As[BK][BM + 4];
  __shared__ float Bs[BK][BN];

  const int bn = blockIdx.x;
  const int bm = blockIdx.y;
  const int tid = threadIdx.x;
  const int tr = tid >> 4, tc = tid & 15;
  const int m0 = bm * BM, n0 = bn * BN;

  float acc[8][8] = {};

  for (int k0 = 0; k0 < Cc; k0 += BK) {
    #pragma unroll
    for (int s = 0; s < 2; ++s) {
      int f4 = tid + s * 256;
      int row = f4 >> 2;
      int c4 = (f4 & 3) * 4;
      float4 av = *(const float4*)&A[(size_t)(m0 + row) * Cc + k0 + c4];
      As[c4 + 0][row] = av.x;
      As[c4 + 1][row] = av.y;
      As[c4 + 2][row] = av.z;
      As[c4 + 3][row] = av.w;
    }
    #pragma unroll
    for (int s = 0; s < 2; ++s) {
      int f4 = tid + s * 256;
      int row = f4 >> 5;
      int c4 = (f4 & 31) * 4;
      *(float4*)&Bs[row][c4] =
          *(const float4*)&Bw[(size_t)(k0 + row) * Cc + n0 + c4];
    }
    __syncthreads();

    #pragma unroll
    for (int k = 0; k < BK; ++k) {
      float a[8], bb[8];
      *(float4*)&a[0] = *(const float4*)&As[k][tr * 8];
      *(float4*)&a[4] = *(const float4*)&As[k][tr * 8 + 4];
      *(float4*)&bb[0] = *(const float4*)&Bs[k][tc * 8];
      *(float4*)&bb[4] = *(const float4*)&Bs[k][tc * 8 + 4];
      #pragma unroll
      for (int i = 0; i < 8; ++i)
        #pragma unroll
        for (int j = 0; j < 8; ++j)
          acc[i][j] = fmaf(a[i], bb[j], acc[i][j]);
    }
    __syncthreads();
  }

  float bv[8];
  #pragma unroll
  for (int j = 0; j < 8; ++j) bv[j] = bias[n0 + tc * 8 + j];

  #pragma unroll
  for (int i = 0; i < 8; ++i) {
    int m = m0 + tr * 8 + i;
    float4 r0, r1;
    r0.x = acc[i][0] + bv[0]; r0.y = acc[i][1] + bv[1];
    r0.z = acc[i][2] + bv[2]; r0.w = acc[i][3] + bv[3];
    r1.x = acc[i][4] + bv[4]; r1.y = acc[i][5] + bv[5];
    r1.z = acc[i][6] + bv[6]; r1.w = acc[i][7] + bv[7];
    *(float4*)&out[(size_t)m * Cc + n0 + tc * 8] = r0;
    *(float4*)&out[(size_t)m * Cc + n0 + tc * 8 + 4] = r1;
  }
}

// ---------------------------------------------------------------------------
extern "C" void kernel_launch(void* const* d_in, const int* in_sizes, int n_in,
                              void* d_out, int out_size, void* d_ws, size_t ws_size,
                              hipStream_t stream) {
  const float* x      = (const float*)d_in[0];
  const float* w_qkv  = (const float*)d_in[1];
  const float* w_proj = (const float*)d_in[2];
  const float* b_proj = (const float*)d_in[3];
  float* out = (float*)d_out;

  float* qkvws = (float*)d_ws;                               // 3*96*1024*64 f32
  float* aout  = qkvws + (size_t)3 * BH * Nn * Dd;           // 8192*768 f32

  dim3 g1(QKVN / 128, Mtot / 128);
  gemm_qkv<<<g1, 256, 0, stream>>>(x, w_qkv, qkvws);

  attn<<<BH * (Nn / 64), 256, 0, stream>>>(qkvws, aout);

  dim3 g3(Cc / 128, Mtot / 128);
  gemm_proj<<<g3, 256, 0, stream>>>(aout, w_proj, b_proj, out);
}

// Round 9
// 620.432 us; speedup vs baseline: 5.2562x; 1.5553x over previous
//
#include <hip/hip_runtime.h>

// Problem constants (fixed by setup_inputs)
constexpr int Bb = 8, Nn = 1024, Cc = 768, Hh = 12, Dd = 64;
constexpr int Mtot = Bb * Nn;          // 8192
constexpr int QKVN = 3 * Cc;           // 2304
constexpr int BH = Bb * Hh;            // 96

typedef __attribute__((ext_vector_type(8))) short short8b;   // 8 bf16 (4 VGPR)
typedef __attribute__((ext_vector_type(4))) float f32x4;
typedef __attribute__((ext_vector_type(4))) unsigned short u16x4;

// f32 -> bf16 (RNE)
__device__ inline unsigned short bf16_hi(float f) {
  unsigned int u = __float_as_uint(f);
  unsigned int r = (u + 0x7FFFu + ((u >> 16) & 1u)) >> 16;
  return (unsigned short)r;
}
__device__ inline float bf16_to_f32(unsigned short h) {
  return __uint_as_float(((unsigned int)h) << 16);
}

// ---------------------------------------------------------------------------
// transpose_split: in f32 [K][N] -> outTh/outTl bf16 [N][K] (hi/lo planes)
// ---------------------------------------------------------------------------
__global__ __launch_bounds__(256)
void transpose_split(const float* __restrict__ in, unsigned short* __restrict__ Th,
                     unsigned short* __restrict__ Tl, int K, int N) {
  __shared__ float tile[32][33];
  const int tx = threadIdx.x & 31;
  const int ty = threadIdx.x >> 5;          // 0..7
  const int gk = blockIdx.y * 32;           // k tile base
  const int gn = blockIdx.x * 32;           // n tile base

  #pragma unroll
  for (int i = 0; i < 4; ++i) {
    int k = gk + ty + 8 * i;
    tile[ty + 8 * i][tx] = in[(size_t)k * N + gn + tx];
  }
  __syncthreads();
  #pragma unroll
  for (int i = 0; i < 4; ++i) {
    int n = gn + ty + 8 * i;
    float v = tile[tx][ty + 8 * i];
    unsigned short h = bf16_hi(v);
    float fl = v - bf16_to_f32(h);
    Th[(size_t)n * K + gk + tx] = h;
    Tl[(size_t)n * K + gk + tx] = bf16_hi(fl);
  }
}

// ---------------------------------------------------------------------------
// gemm_mfma: C[M][N] = A[M][K]_f32 @ B[K][N]  (B given pre-transposed+split:
// BTh/BTl bf16 [N][K]).  Split-bf16 3-term MFMA (AhBh + AhBl + AlBh).
// Tile 128x128, BK=32, 256 thr = 4 waves (2x2), each wave 64x64 out
// = 4x4 tiles of mfma_f32_16x16x32_bf16.
// EPI 0: scatter into qkv_ws [3][96][1024][64].  EPI 1: +bias -> out.
// ---------------------------------------------------------------------------
template <int EPI>
__global__ __launch_bounds__(256)
void gemm_mfma(const float* __restrict__ A, const unsigned short* __restrict__ BTh,
               const unsigned short* __restrict__ BTl, const float* __restrict__ bias,
               float* __restrict__ Cout, int K, int Ncols) {
  constexpr int LDH = 40;                   // LDS row stride (halfwords): 32 + 8 pad
  __shared__ unsigned short Ah[128][LDH], Al[128][LDH];
  __shared__ unsigned short Bh[128][LDH], Bl[128][LDH];

  const int tid = threadIdx.x;
  const int lane = tid & 63;
  const int w = tid >> 6;                   // 0..3
  const int wm = (w & 1) * 64, wn = (w >> 1) * 64;
  const int m0 = blockIdx.y * 128, n0 = blockIdx.x * 128;

  const int srow = tid >> 1;                // 0..127 (staging row)
  const int sko = (tid & 1) * 16;           // 0 or 16 (staging k offset)

  f32x4 acc[4][4];
  #pragma unroll
  for (int i = 0; i < 4; ++i)
    #pragma unroll
    for (int j = 0; j < 4; ++j) acc[i][j] = (f32x4)0.f;

  const int lr = lane & 15;                 // fragment row/col
  const int lk = (lane >> 4) * 8;           // fragment k base

  for (int k0 = 0; k0 < K; k0 += 32) {
    __syncthreads();                        // readers of prev iter done
    // --- stage A: f32 -> hi/lo bf16 (16 halfwords per thread) ---
    {
      const float* ap = &A[(size_t)(m0 + srow) * K + k0 + sko];
      #pragma unroll
      for (int i = 0; i < 4; ++i) {
        float4 v = *(const float4*)&ap[4 * i];
        u16x4 h, l;
        float f[4] = {v.x, v.y, v.z, v.w};
        #pragma unroll
        for (int e = 0; e < 4; ++e) {
          unsigned short hh = bf16_hi(f[e]);
          h[e] = hh;
          l[e] = bf16_hi(f[e] - bf16_to_f32(hh));
        }
        *(u16x4*)&Ah[srow][sko + 4 * i] = h;
        *(u16x4*)&Al[srow][sko + 4 * i] = l;
      }
    }
    // --- stage B: pre-split bf16 copy (16 halfwords per thread!) ---
    // R7 BUG WAS HERE: only 8 of 16 halfwords were written, leaving
    // Bh/Bl[*][8..15] and [24..31] as uninitialized LDS -> NaN fragments.
    {
      const unsigned short* bhp = &BTh[(size_t)(n0 + srow) * K + k0 + sko];
      const unsigned short* blp = &BTl[(size_t)(n0 + srow) * K + k0 + sko];
      *(short8b*)&Bh[srow][sko]     = *(const short8b*)bhp;
      *(short8b*)&Bh[srow][sko + 8] = *(const short8b*)(bhp + 8);
      *(short8b*)&Bl[srow][sko]     = *(const short8b*)blp;
      *(short8b*)&Bl[srow][sko + 8] = *(const short8b*)(blp + 8);
    }
    __syncthreads();

    // --- fragments + MFMA ---
    short8b ahf[4], alf[4], bhf[4], blf[4];
    #pragma unroll
    for (int mi = 0; mi < 4; ++mi) {
      ahf[mi] = *(const short8b*)&Ah[wm + mi * 16 + lr][lk];
      alf[mi] = *(const short8b*)&Al[wm + mi * 16 + lr][lk];
    }
    #pragma unroll
    for (int nj = 0; nj < 4; ++nj) {
      bhf[nj] = *(const short8b*)&Bh[wn + nj * 16 + lr][lk];
      blf[nj] = *(const short8b*)&Bl[wn + nj * 16 + lr][lk];
    }
    #pragma unroll
    for (int mi = 0; mi < 4; ++mi)
      #pragma unroll
      for (int nj = 0; nj < 4; ++nj) {
        acc[mi][nj] = __builtin_amdgcn_mfma_f32_16x16x32_bf16(
            ahf[mi], bhf[nj], acc[mi][nj], 0, 0, 0);
        acc[mi][nj] = __builtin_amdgcn_mfma_f32_16x16x32_bf16(
            ahf[mi], blf[nj], acc[mi][nj], 0, 0, 0);
        acc[mi][nj] = __builtin_amdgcn_mfma_f32_16x16x32_bf16(
            alf[mi], bhf[nj], acc[mi][nj], 0, 0, 0);
      }
  }

  // --- epilogue ---  D: col = lane&15, row = (lane>>4)*4 + r
  #pragma unroll
  for (int mi = 0; mi < 4; ++mi) {
    #pragma unroll
    for (int nj = 0; nj < 4; ++nj) {
      #pragma unroll
      for (int r = 0; r < 4; ++r) {
        int m = m0 + wm + mi * 16 + (lane >> 4) * 4 + r;
        int n = n0 + wn + nj * 16 + lr;
        float v = acc[mi][nj][r];
        if (EPI == 0) {
          // e = t*768 + h*64 + d ; dst [t][b*12+h][nn][d]
          int t = n0 / Cc;                 // uniform (128 | 768)
          int rem = n - t * Cc;
          int h = rem >> 6, d = rem & 63;
          int bI = m >> 10, nI = m & 1023;
          Cout[(((size_t)t * BH + bI * Hh + h) * Nn + nI) * Dd + d] = v;
        } else {
          Cout[(size_t)m * Cc + n] = v + bias[n];
        }
      }
    }
  }
}

// ---------------------------------------------------------------------------
// attention (verified R5 version, UNCHANGED)
// ---------------------------------------------------------------------------
__global__ __launch_bounds__(256)
void attn(const float* __restrict__ qkv_ws, float* __restrict__ aout) {
  constexpr int LDW = 68;
  __shared__ float Qs[64][LDW];
  __shared__ float KPs[64][LDW];
  __shared__ float Vs[64][LDW];

  const int bid = blockIdx.x;
  const int bh = bid >> 4;
  const int qt = bid & 15;
  const int b = bh / Hh, h = bh % Hh;
  const int tid = threadIdx.x;
  const int tr = tid >> 4;
  const int tc = tid & 15;

  const float* Qg = qkv_ws + ((size_t)bh * Nn + qt * 64) * Dd;
  const float* Kg = qkv_ws + ((size_t)(BH + bh) * Nn) * Dd;
  const float* Vg = qkv_ws + ((size_t)(2 * BH + bh) * Nn) * Dd;

  #pragma unroll
  for (int s = 0; s < 4; ++s) {
    int f4 = s * 256 + tid;
    int row = f4 >> 4;
    int c4 = (f4 & 15) * 4;
    float4 v = *(const float4*)&Qg[row * 64 + c4];
    Qs[c4 + 0][row] = v.x; Qs[c4 + 1][row] = v.y;
    Qs[c4 + 2][row] = v.z; Qs[c4 + 3][row] = v.w;
  }

  float o[4][4] = {};
  float mrow[4] = {-1e30f, -1e30f, -1e30f, -1e30f};
  float lrow[4] = {};
  const float scale = 0.125f;

  for (int kt = 0; kt < 16; ++kt) {
    __syncthreads();
    #pragma unroll
    for (int s = 0; s < 4; ++s) {
      int f4 = s * 256 + tid;
      int row = f4 >> 4;
      int c4 = (f4 & 15) * 4;
      float4 kv4 = *(const float4*)&Kg[(size_t)(kt * 64 + row) * 64 + c4];
      KPs[c4 + 0][row] = kv4.x; KPs[c4 + 1][row] = kv4.y;
      KPs[c4 + 2][row] = kv4.z; KPs[c4 + 3][row] = kv4.w;
      float4 vv4 = *(const float4*)&Vg[(size_t)(kt * 64 + row) * 64 + c4];
      *(float4*)&Vs[row][c4] = vv4;
    }
    __syncthreads();

    float sv[4][4] = {};
    #pragma unroll 4
    for (int k = 0; k < 64; ++k) {
      float a[4], bb[4];
      *(float4*)&a[0]  = *(const float4*)&Qs[k][tr * 4];
      *(float4*)&bb[0] = *(const float4*)&KPs[k][tc * 4];
      #pragma unroll
      for (int i = 0; i < 4; ++i)
        #pragma unroll
        for (int j = 0; j < 4; ++j)
          sv[i][j] = fmaf(a[i], bb[j], sv[i][j]);
    }

    float p[4][4];
    #pragma unroll
    for (int i = 0; i < 4; ++i) {
      #pragma unroll
      for (int j = 0; j < 4; ++j) sv[i][j] *= scale;
      float t0 = fmaxf(fmaxf(sv[i][0], sv[i][1]), fmaxf(sv[i][2], sv[i][3]));
      #pragma unroll
      for (int m = 1; m < 16; m <<= 1) t0 = fmaxf(t0, __shfl_xor(t0, m));
      float mn = fmaxf(mrow[i], t0);
      float corr = __expf(mrow[i] - mn);
      mrow[i] = mn;
      lrow[i] *= corr;
      #pragma unroll
      for (int j = 0; j < 4; ++j) o[i][j] *= corr;
      float s0 = 0.f;
      #pragma unroll
      for (int j = 0; j < 4; ++j) {
        p[i][j] = __expf(sv[i][j] - mn);
        s0 += p[i][j];
      }
      #pragma unroll
      for (int m = 1; m < 16; m <<= 1) s0 += __shfl_xor(s0, m);
      lrow[i] += s0;
    }

    __syncthreads();
    #pragma unroll
    for (int j = 0; j < 4; ++j) {
      float4 pc;
      pc.x = p[0][j]; pc.y = p[1][j]; pc.z = p[2][j]; pc.w = p[3][j];
      *(float4*)&KPs[tc * 4 + j][tr * 4] = pc;
    }
    __syncthreads();

    #pragma unroll 4
    for (int c = 0; c < 64; ++c) {
      float a[4], bb[4];
      *(float4*)&a[0]  = *(const float4*)&KPs[c][tr * 4];
      *(float4*)&bb[0] = *(const float4*)&Vs[c][tc * 4];
      #pragma unroll
      for (int i = 0; i < 4; ++i)
        #pragma unroll
        for (int j = 0; j < 4; ++j)
          o[i][j] = fmaf(a[i], bb[j], o[i][j]);
    }
  }

  #pragma unroll
  for (int i = 0; i < 4; ++i) {
    float inv = 1.0f / lrow[i];
    float4 r;
    r.x = o[i][0] * inv; r.y = o[i][1] * inv;
    r.z = o[i][2] * inv; r.w = o[i][3] * inv;
    *(float4*)&aout[((size_t)(b * Nn + qt * 64 + tr * 4 + i)) * Cc + h * 64 + tc * 4] = r;
  }
}

// ---------------------------------------------------------------------------
// Workspace plan — fits in the R2-R5-PROVEN 100,663,296 bytes via aliasing.
//   region A: [0, 75,497,472)          qkv_ws  (later: wprojTh/Tl at base)
//   region B: [75,497,472, 100,663,296) wqkvTh/Tl (later: aout)
// Timeline (stream-serial):
//   1. tsplit(w_qkv)  -> wqkvT in region B
//   2. gemm<0>        reads wqkvT, writes qkv_ws (region A)
//   3. attn           reads qkv_ws, writes aout over region B (wqkvT dead)
//   4. tsplit(w_proj) -> wprojT at base of region A (qkv_ws dead)
//   5. gemm<1>        reads aout + wprojT, writes d_out
// ---------------------------------------------------------------------------
extern "C" void kernel_launch(void* const* d_in, const int* in_sizes, int n_in,
                              void* d_out, int out_size, void* d_ws, size_t ws_size,
                              hipStream_t stream) {
  const float* x      = (const float*)d_in[0];
  const float* w_qkv  = (const float*)d_in[1];
  const float* w_proj = (const float*)d_in[2];
  const float* b_proj = (const float*)d_in[3];
  float* out = (float*)d_out;

  char* ws = (char*)d_ws;
  float* qkv_ws           = (float*)ws;                        // 75,497,472 B
  unsigned short* wprojTh = (unsigned short*)ws;               // aliases qkv_ws (phase 4+)
  unsigned short* wprojTl = (unsigned short*)(ws + 1179648);   // 1,179,648 B each
  unsigned short* wqkvTh  = (unsigned short*)(ws + 75497472);  // 3,538,944 B
  unsigned short* wqkvTl  = (unsigned short*)(ws + 79036416);  // 3,538,944 B
  float* aout             = (float*)(ws + 75497472);           // 25,165,824 B (aliases wqkvT)

  // 1) split+transpose w_qkv into region B
  transpose_split<<<dim3(QKVN / 32, Cc / 32), 256, 0, stream>>>(w_qkv, wqkvTh, wqkvTl, Cc, QKVN);

  // 2) QKV GEMM (MFMA split-bf16), scatter to q/k/v in region A
  gemm_mfma<0><<<dim3(QKVN / 128, Mtot / 128), 256, 0, stream>>>(
      x, wqkvTh, wqkvTl, nullptr, qkv_ws, Cc, QKVN);

  // 3) attention: reads region A, writes aout over region B
  attn<<<BH * (Nn / 64), 256, 0, stream>>>(qkv_ws, aout);

  // 4) split+transpose w_proj into (now dead) region A base
  transpose_split<<<dim3(Cc / 32, Cc / 32), 256, 0, stream>>>(w_proj, wprojTh, wprojTl, Cc, Cc);

  // 5) proj GEMM (MFMA split-bf16) + bias -> out
  gemm_mfma<1><<<dim3(Cc / 128, Mtot / 128), 256, 0, stream>>>(
      aout, wprojTh, wprojTl, b_proj, out, Cc, Cc);
}

// Round 11
// 406.918 us; speedup vs baseline: 8.0142x; 1.5247x over previous
//
#include <hip/hip_runtime.h>

// Problem constants (fixed by setup_inputs)
constexpr int Bb = 8, Nn = 1024, Cc = 768, Hh = 12, Dd = 64;
constexpr int Mtot = Bb * Nn;          // 8192
constexpr int QKVN = 3 * Cc;           // 2304
constexpr int BH = Bb * Hh;            // 96

typedef __attribute__((ext_vector_type(8))) short short8b;   // 8 bf16 (4 VGPR)
typedef __attribute__((ext_vector_type(4))) float f32x4;
typedef __attribute__((ext_vector_type(4))) unsigned short u16x4;

// f32 -> bf16 (RNE)
__device__ inline unsigned short bf16_hi(float f) {
  unsigned int u = __float_as_uint(f);
  unsigned int r = (u + 0x7FFFu + ((u >> 16) & 1u)) >> 16;
  return (unsigned short)r;
}
__device__ inline float bf16_to_f32(unsigned short h) {
  return __uint_as_float(((unsigned int)h) << 16);
}

// ---------------------------------------------------------------------------
// transpose_split (verified R9, unchanged)
// ---------------------------------------------------------------------------
__global__ __launch_bounds__(256)
void transpose_split(const float* __restrict__ in, unsigned short* __restrict__ Th,
                     unsigned short* __restrict__ Tl, int K, int N) {
  __shared__ float tile[32][33];
  const int tx = threadIdx.x & 31;
  const int ty = threadIdx.x >> 5;
  const int gk = blockIdx.y * 32;
  const int gn = blockIdx.x * 32;

  #pragma unroll
  for (int i = 0; i < 4; ++i) {
    int k = gk + ty + 8 * i;
    tile[ty + 8 * i][tx] = in[(size_t)k * N + gn + tx];
  }
  __syncthreads();
  #pragma unroll
  for (int i = 0; i < 4; ++i) {
    int n = gn + ty + 8 * i;
    float v = tile[tx][ty + 8 * i];
    unsigned short h = bf16_hi(v);
    float fl = v - bf16_to_f32(h);
    Th[(size_t)n * K + gk + tx] = h;
    Tl[(size_t)n * K + gk + tx] = bf16_hi(fl);
  }
}

// ---------------------------------------------------------------------------
// gemm_mfma (verified R9, unchanged)
// ---------------------------------------------------------------------------
template <int EPI>
__global__ __launch_bounds__(256)
void gemm_mfma(const float* __restrict__ A, const unsigned short* __restrict__ BTh,
               const unsigned short* __restrict__ BTl, const float* __restrict__ bias,
               float* __restrict__ Cout, int K, int Ncols) {
  constexpr int LDH = 40;
  __shared__ unsigned short Ah[128][LDH], Al[128][LDH];
  __shared__ unsigned short Bh[128][LDH], Bl[128][LDH];

  const int tid = threadIdx.x;
  const int lane = tid & 63;
  const int w = tid >> 6;
  const int wm = (w & 1) * 64, wn = (w >> 1) * 64;
  const int m0 = blockIdx.y * 128, n0 = blockIdx.x * 128;

  const int srow = tid >> 1;
  const int sko = (tid & 1) * 16;

  f32x4 acc[4][4];
  #pragma unroll
  for (int i = 0; i < 4; ++i)
    #pragma unroll
    for (int j = 0; j < 4; ++j) acc[i][j] = (f32x4)0.f;

  const int lr = lane & 15;
  const int lk = (lane >> 4) * 8;

  for (int k0 = 0; k0 < K; k0 += 32) {
    __syncthreads();
    {
      const float* ap = &A[(size_t)(m0 + srow) * K + k0 + sko];
      #pragma unroll
      for (int i = 0; i < 4; ++i) {
        float4 v = *(const float4*)&ap[4 * i];
        u16x4 h, l;
        float f[4] = {v.x, v.y, v.z, v.w};
        #pragma unroll
        for (int e = 0; e < 4; ++e) {
          unsigned short hh = bf16_hi(f[e]);
          h[e] = hh;
          l[e] = bf16_hi(f[e] - bf16_to_f32(hh));
        }
        *(u16x4*)&Ah[srow][sko + 4 * i] = h;
        *(u16x4*)&Al[srow][sko + 4 * i] = l;
      }
    }
    {
      const unsigned short* bhp = &BTh[(size_t)(n0 + srow) * K + k0 + sko];
      const unsigned short* blp = &BTl[(size_t)(n0 + srow) * K + k0 + sko];
      *(short8b*)&Bh[srow][sko]     = *(const short8b*)bhp;
      *(short8b*)&Bh[srow][sko + 8] = *(const short8b*)(bhp + 8);
      *(short8b*)&Bl[srow][sko]     = *(const short8b*)blp;
      *(short8b*)&Bl[srow][sko + 8] = *(const short8b*)(blp + 8);
    }
    __syncthreads();

    short8b ahf[4], alf[4], bhf[4], blf[4];
    #pragma unroll
    for (int mi = 0; mi < 4; ++mi) {
      ahf[mi] = *(const short8b*)&Ah[wm + mi * 16 + lr][lk];
      alf[mi] = *(const short8b*)&Al[wm + mi * 16 + lr][lk];
    }
    #pragma unroll
    for (int nj = 0; nj < 4; ++nj) {
      bhf[nj] = *(const short8b*)&Bh[wn + nj * 16 + lr][lk];
      blf[nj] = *(const short8b*)&Bl[wn + nj * 16 + lr][lk];
    }
    #pragma unroll
    for (int mi = 0; mi < 4; ++mi)
      #pragma unroll
      for (int nj = 0; nj < 4; ++nj) {
        acc[mi][nj] = __builtin_amdgcn_mfma_f32_16x16x32_bf16(
            ahf[mi], bhf[nj], acc[mi][nj], 0, 0, 0);
        acc[mi][nj] = __builtin_amdgcn_mfma_f32_16x16x32_bf16(
            ahf[mi], blf[nj], acc[mi][nj], 0, 0, 0);
        acc[mi][nj] = __builtin_amdgcn_mfma_f32_16x16x32_bf16(
            alf[mi], bhf[nj], acc[mi][nj], 0, 0, 0);
      }
  }

  #pragma unroll
  for (int mi = 0; mi < 4; ++mi) {
    #pragma unroll
    for (int nj = 0; nj < 4; ++nj) {
      #pragma unroll
      for (int r = 0; r < 4; ++r) {
        int m = m0 + wm + mi * 16 + (lane >> 4) * 4 + r;
        int n = n0 + wn + nj * 16 + lr;
        float v = acc[mi][nj][r];
        if (EPI == 0) {
          int t = n0 / Cc;
          int rem = n - t * Cc;
          int h = rem >> 6, d = rem & 63;
          int bI = m >> 10, nI = m & 1023;
          Cout[(((size_t)t * BH + bI * Hh + h) * Nn + nI) * Dd + d] = v;
        } else {
          Cout[(size_t)m * Cc + n] = v + bias[n];
        }
      }
    }
  }
}

// ---------------------------------------------------------------------------
// attn_mfma: flash attention on the matrix pipe, split-bf16 3-term.
// Block = 256 thr = 4 waves; wave wv owns q-band [wv*16, wv*16+16).
// Per KV tile (64): S^T = K·Q^T (D rows=kv, cols=q) -> lane-local online
// softmax (qp = lane&15 personality) -> P to LDS (hi/lo, u32-packed)
// -> O += P·V with V staged transposed (B-frags contiguous b128).
// All four fragment addressing forms identical to the R9-verified GEMM.
// ---------------------------------------------------------------------------
__global__ __launch_bounds__(256)
void attn_mfma(const float* __restrict__ qkv_ws, float* __restrict__ aout) {
  constexpr int LDH2 = 72;              // halfword stride: 144 B, 16B-aligned rows
  __shared__ unsigned short Qh[64][LDH2], Ql[64][LDH2];
  __shared__ unsigned short Ksh[64][LDH2], Ksl[64][LDH2];
  __shared__ unsigned short Vth[64][LDH2], Vtl[64][LDH2];
  __shared__ unsigned short Ph[64][LDH2], Pl[64][LDH2];

  const int bid = blockIdx.x;           // 0..1535
  const int bh = bid >> 4, qt = bid & 15;
  const int b = bh / Hh, h = bh % Hh;
  const int tid = threadIdx.x;
  const int lane = tid & 63;
  const int wv = tid >> 6;              // 0..3
  const int q0 = wv * 16;               // wave's q-band base
  const int qp = lane & 15;             // q' personality / frag row-col
  const int g  = lane >> 4;             // 0..3

  const float* Qg = qkv_ws + ((size_t)bh * Nn + qt * 64) * Dd;
  const float* Kg = qkv_ws + ((size_t)(BH + bh) * Nn) * Dd;
  const float* Vg = qkv_ws + ((size_t)(2 * BH + bh) * Nn) * Dd;
  const float scale = 0.125f;           // 64^-0.5

  // ---- stage Q hi/lo (once) ----
  #pragma unroll
  for (int s = 0; s < 4; ++s) {
    int f = s * 256 + tid;
    int row = f >> 4, c4 = (f & 15) * 4;
    float4 v = *(const float4*)&Qg[row * 64 + c4];
    float fv[4] = {v.x, v.y, v.z, v.w};
    u16x4 hh, ll;
    #pragma unroll
    for (int e = 0; e < 4; ++e) {
      unsigned short x = bf16_hi(fv[e]);
      hh[e] = x; ll[e] = bf16_hi(fv[e] - bf16_to_f32(x));
    }
    *(u16x4*)&Qh[row][c4] = hh;
    *(u16x4*)&Ql[row][c4] = ll;
  }
  __syncthreads();
  // Q B-fragments to registers (invariant over all KV tiles)
  short8b qfh[2], qfl[2];
  #pragma unroll
  for (int ks = 0; ks < 2; ++ks) {
    qfh[ks] = *(const short8b*)&Qh[q0 + qp][ks * 32 + g * 8];
    qfl[ks] = *(const short8b*)&Ql[q0 + qp][ks * 32 + g * 8];
  }

  f32x4 acc_o[4];                       // O[q0+4g+r][dt*16+qp]
  #pragma unroll
  for (int dt = 0; dt < 4; ++dt) acc_o[dt] = (f32x4)0.f;
  float mrun = -1e30f, lrun = 0.f;      // per-lane state for q = q0 + qp

  for (int kt = 0; kt < 16; ++kt) {
    __syncthreads();                    // prior tile's frag readers done
    // ---- stage K hi/lo (natural [kv][d]) ----
    #pragma unroll
    for (int s = 0; s < 4; ++s) {
      int f = s * 256 + tid;
      int row = f >> 4, c4 = (f & 15) * 4;
      float4 v = *(const float4*)&Kg[(size_t)(kt * 64 + row) * 64 + c4];
      float fv[4] = {v.x, v.y, v.z, v.w};
      u16x4 hh, ll;
      #pragma unroll
      for (int e = 0; e < 4; ++e) {
        unsigned short x = bf16_hi(fv[e]);
        hh[e] = x; ll[e] = bf16_hi(fv[e] - bf16_to_f32(x));
      }
      *(u16x4*)&Ksh[row][c4] = hh;
      *(u16x4*)&Ksl[row][c4] = ll;
    }
    // ---- stage V TRANSPOSED hi/lo: Vt[d][kv], u32-packed kv-pairs ----
    #pragma unroll
    for (int s = 0; s < 2; ++s) {
      int f = s * 256 + tid;
      int kv2 = (f >> 4) * 2, c4 = (f & 15) * 4;
      float4 v0 = *(const float4*)&Vg[(size_t)(kt * 64 + kv2) * 64 + c4];
      float4 v1 = *(const float4*)&Vg[(size_t)(kt * 64 + kv2 + 1) * 64 + c4];
      float a0[4] = {v0.x, v0.y, v0.z, v0.w};
      float a1[4] = {v1.x, v1.y, v1.z, v1.w};
      #pragma unroll
      for (int e = 0; e < 4; ++e) {
        unsigned short h0 = bf16_hi(a0[e]), h1 = bf16_hi(a1[e]);
        unsigned short l0 = bf16_hi(a0[e] - bf16_to_f32(h0));
        unsigned short l1 = bf16_hi(a1[e] - bf16_to_f32(h1));
        *(unsigned int*)&Vth[c4 + e][kv2] = (unsigned)h0 | ((unsigned)h1 << 16);
        *(unsigned int*)&Vtl[c4 + e][kv2] = (unsigned)l0 | ((unsigned)l1 << 16);
      }
    }
    __syncthreads();                    // staging visible

    // ---- S^T = K·Q^T  (D[kv][q]; lane: kv = kb*16+4g+r, q = q0+qp) ----
    f32x4 sacc[4];
    #pragma unroll
    for (int kb = 0; kb < 4; ++kb) sacc[kb] = (f32x4)0.f;
    #pragma unroll
    for (int kb = 0; kb < 4; ++kb) {
      #pragma unroll
      for (int ks = 0; ks < 2; ++ks) {
        short8b kfh = *(const short8b*)&Ksh[kb * 16 + qp][ks * 32 + g * 8];
        short8b kfl = *(const short8b*)&Ksl[kb * 16 + qp][ks * 32 + g * 8];
        sacc[kb] = __builtin_amdgcn_mfma_f32_16x16x32_bf16(kfh, qfh[ks], sacc[kb], 0, 0, 0);
        sacc[kb] = __builtin_amdgcn_mfma_f32_16x16x32_bf16(kfh, qfl[ks], sacc[kb], 0, 0, 0);
        sacc[kb] = __builtin_amdgcn_mfma_f32_16x16x32_bf16(kfl, qfh[ks], sacc[kb], 0, 0, 0);
      }
    }

    // ---- online softmax (state keyed to q = q0+qp) ----
    float sv[16];
    #pragma unroll
    for (int kb = 0; kb < 4; ++kb)
      #pragma unroll
      for (int r = 0; r < 4; ++r) sv[kb * 4 + r] = sacc[kb][r] * scale;
    float tmax = sv[0];
    #pragma unroll
    for (int i = 1; i < 16; ++i) tmax = fmaxf(tmax, sv[i]);
    tmax = fmaxf(tmax, __shfl_xor(tmax, 16));
    tmax = fmaxf(tmax, __shfl_xor(tmax, 32));
    float mn = fmaxf(mrun, tmax);
    float corr = __expf(mrun - mn);
    float pv[16];
    float psum = 0.f;
    #pragma unroll
    for (int i = 0; i < 16; ++i) { pv[i] = __expf(sv[i] - mn); psum += pv[i]; }
    psum += __shfl_xor(psum, 16);
    psum += __shfl_xor(psum, 32);
    lrun = lrun * corr + psum;
    mrun = mn;
    // rescale O: need corr for q-rows q0+4g+r (lane 4g+r holds it, qp==4g+r)
    #pragma unroll
    for (int r = 0; r < 4; ++r) {
      float cr = __shfl(corr, g * 4 + r);
      #pragma unroll
      for (int dt = 0; dt < 4; ++dt) acc_o[dt][r] *= cr;
    }

    // ---- P -> LDS hi/lo (row q0+qp, kv = kb*16+4g+{0..3}, u32 pairs) ----
    #pragma unroll
    for (int kb = 0; kb < 4; ++kb) {
      unsigned short ph[4], plo[4];
      #pragma unroll
      for (int r = 0; r < 4; ++r) {
        ph[r] = bf16_hi(pv[kb * 4 + r]);
        plo[r] = bf16_hi(pv[kb * 4 + r] - bf16_to_f32(ph[r]));
      }
      int base = kb * 16 + g * 4;
      *(unsigned int*)&Ph[q0 + qp][base]     = (unsigned)ph[0] | ((unsigned)ph[1] << 16);
      *(unsigned int*)&Ph[q0 + qp][base + 2] = (unsigned)ph[2] | ((unsigned)ph[3] << 16);
      *(unsigned int*)&Pl[q0 + qp][base]     = (unsigned)plo[0] | ((unsigned)plo[1] << 16);
      *(unsigned int*)&Pl[q0 + qp][base + 2] = (unsigned)plo[2] | ((unsigned)plo[3] << 16);
    }
    __syncthreads();                    // conservative: P layout-exchange visible

    // ---- O += P·V  (A=P[q][kv], B=V[kv][d] from Vt[d][kv]) ----
    short8b pfh[2], pfl[2];
    #pragma unroll
    for (int ks = 0; ks < 2; ++ks) {
      pfh[ks] = *(const short8b*)&Ph[q0 + qp][ks * 32 + g * 8];
      pfl[ks] = *(const short8b*)&Pl[q0 + qp][ks * 32 + g * 8];
    }
    #pragma unroll
    for (int dt = 0; dt < 4; ++dt) {
      #pragma unroll
      for (int ks = 0; ks < 2; ++ks) {
        short8b vfh = *(const short8b*)&Vth[dt * 16 + qp][ks * 32 + g * 8];
        short8b vfl = *(const short8b*)&Vtl[dt * 16 + qp][ks * 32 + g * 8];
        acc_o[dt] = __builtin_amdgcn_mfma_f32_16x16x32_bf16(pfh[ks], vfh, acc_o[dt], 0, 0, 0);
        acc_o[dt] = __builtin_amdgcn_mfma_f32_16x16x32_bf16(pfh[ks], vfl, acc_o[dt], 0, 0, 0);
        acc_o[dt] = __builtin_amdgcn_mfma_f32_16x16x32_bf16(pfl[ks], vfh, acc_o[dt], 0, 0, 0);
      }
    }
  }

  // ---- epilogue: normalize rows, write [b][n][h*64+d] ----
  float linv = 1.0f / lrun;
  #pragma unroll
  for (int r = 0; r < 4; ++r) {
    float lr = __shfl(linv, g * 4 + r);
    int q = qt * 64 + q0 + 4 * g + r;
    #pragma unroll
    for (int dt = 0; dt < 4; ++dt) {
      aout[((size_t)(b * Nn + q)) * Cc + h * 64 + dt * 16 + qp] = acc_o[dt][r] * lr;
    }
  }
}

// ---------------------------------------------------------------------------
// Workspace: R9-proven aliasing plan (100,663,296 B total, unchanged)
// ---------------------------------------------------------------------------
extern "C" void kernel_launch(void* const* d_in, const int* in_sizes, int n_in,
                              void* d_out, int out_size, void* d_ws, size_t ws_size,
                              hipStream_t stream) {
  const float* x      = (const float*)d_in[0];
  const float* w_qkv  = (const float*)d_in[1];
  const float* w_proj = (const float*)d_in[2];
  const float* b_proj = (const float*)d_in[3];
  float* out = (float*)d_out;

  char* ws = (char*)d_ws;
  float* qkv_ws           = (float*)ws;
  unsigned short* wprojTh = (unsigned short*)ws;
  unsigned short* wprojTl = (unsigned short*)(ws + 1179648);
  unsigned short* wqkvTh  = (unsigned short*)(ws + 75497472);
  unsigned short* wqkvTl  = (unsigned short*)(ws + 79036416);
  float* aout             = (float*)(ws + 75497472);

  transpose_split<<<dim3(QKVN / 32, Cc / 32), 256, 0, stream>>>(w_qkv, wqkvTh, wqkvTl, Cc, QKVN);

  gemm_mfma<0><<<dim3(QKVN / 128, Mtot / 128), 256, 0, stream>>>(
      x, wqkvTh, wqkvTl, nullptr, qkv_ws, Cc, QKVN);

  attn_mfma<<<BH * (Nn / 64), 256, 0, stream>>>(qkv_ws, aout);

  transpose_split<<<dim3(Cc / 32, Cc / 32), 256, 0, stream>>>(w_proj, wprojTh, wprojTl, Cc, Cc);

  gemm_mfma<1><<<dim3(Cc / 128, Mtot / 128), 256, 0, stream>>>(
      aout, wprojTh, wprojTl, b_proj, out, Cc, Cc);
}

// Round 12
// 362.392 us; speedup vs baseline: 8.9988x; 1.1229x over previous
//
#include <hip/hip_runtime.h>

// Problem constants (fixed by setup_inputs)
constexpr int Bb = 8, Nn = 1024, Cc = 768, Hh = 12, Dd = 64;
constexpr int Mtot = Bb * Nn;          // 8192
constexpr int QKVN = 3 * Cc;           // 2304
constexpr int BH = Bb * Hh;            // 96
constexpr size_t PLANE = (size_t)BH * Nn * Dd;   // 6,291,456 elems (12,582,912 B)

typedef __attribute__((ext_vector_type(8))) short short8b;   // 8 bf16 (4 VGPR)
typedef __attribute__((ext_vector_type(4))) float f32x4;
typedef __attribute__((ext_vector_type(4))) unsigned short u16x4;

// f32 -> bf16 (RNE)
__device__ inline unsigned short bf16_hi(float f) {
  unsigned int u = __float_as_uint(f);
  unsigned int r = (u + 0x7FFFu + ((u >> 16) & 1u)) >> 16;
  return (unsigned short)r;
}
__device__ inline float bf16_to_f32(unsigned short h) {
  return __uint_as_float(((unsigned int)h) << 16);
}

// ---------------------------------------------------------------------------
// transpose_split (verified R9, unchanged)
// ---------------------------------------------------------------------------
__global__ __launch_bounds__(256)
void transpose_split(const float* __restrict__ in, unsigned short* __restrict__ Th,
                     unsigned short* __restrict__ Tl, int K, int N) {
  __shared__ float tile[32][33];
  const int tx = threadIdx.x & 31;
  const int ty = threadIdx.x >> 5;
  const int gk = blockIdx.y * 32;
  const int gn = blockIdx.x * 32;

  #pragma unroll
  for (int i = 0; i < 4; ++i) {
    int k = gk + ty + 8 * i;
    tile[ty + 8 * i][tx] = in[(size_t)k * N + gn + tx];
  }
  __syncthreads();
  #pragma unroll
  for (int i = 0; i < 4; ++i) {
    int n = gn + ty + 8 * i;
    float v = tile[tx][ty + 8 * i];
    unsigned short h = bf16_hi(v);
    float fl = v - bf16_to_f32(h);
    Th[(size_t)n * K + gk + tx] = h;
    Tl[(size_t)n * K + gk + tx] = bf16_hi(fl);
  }
}

// ---------------------------------------------------------------------------
// gemm_mfma (R9-verified core).  EPI 0: write pre-split bf16 planes
// {Qh,Ql,Kh,Kl natural [bh][n][d]; Vth,Vtl transposed [bh][d][n]}.
// EPI 1: +bias -> f32 out.
// ---------------------------------------------------------------------------
template <int EPI>
__global__ __launch_bounds__(256)
void gemm_mfma(const float* __restrict__ A, const unsigned short* __restrict__ BTh,
               const unsigned short* __restrict__ BTl, const float* __restrict__ bias,
               float* __restrict__ Cout, unsigned short* __restrict__ planes, int K) {
  constexpr int LDH = 40;
  __shared__ unsigned short Ah[128][LDH], Al[128][LDH];
  __shared__ unsigned short Bh[128][LDH], Bl[128][LDH];

  const int tid = threadIdx.x;
  const int lane = tid & 63;
  const int w = tid >> 6;
  const int wm = (w & 1) * 64, wn = (w >> 1) * 64;
  const int m0 = blockIdx.y * 128, n0 = blockIdx.x * 128;

  const int srow = tid >> 1;
  const int sko = (tid & 1) * 16;

  f32x4 acc[4][4];
  #pragma unroll
  for (int i = 0; i < 4; ++i)
    #pragma unroll
    for (int j = 0; j < 4; ++j) acc[i][j] = (f32x4)0.f;

  const int lr = lane & 15;
  const int lk = (lane >> 4) * 8;

  for (int k0 = 0; k0 < K; k0 += 32) {
    __syncthreads();
    {
      const float* ap = &A[(size_t)(m0 + srow) * K + k0 + sko];
      #pragma unroll
      for (int i = 0; i < 4; ++i) {
        float4 v = *(const float4*)&ap[4 * i];
        u16x4 h, l;
        float f[4] = {v.x, v.y, v.z, v.w};
        #pragma unroll
        for (int e = 0; e < 4; ++e) {
          unsigned short hh = bf16_hi(f[e]);
          h[e] = hh;
          l[e] = bf16_hi(f[e] - bf16_to_f32(hh));
        }
        *(u16x4*)&Ah[srow][sko + 4 * i] = h;
        *(u16x4*)&Al[srow][sko + 4 * i] = l;
      }
    }
    {
      const unsigned short* bhp = &BTh[(size_t)(n0 + srow) * K + k0 + sko];
      const unsigned short* blp = &BTl[(size_t)(n0 + srow) * K + k0 + sko];
      *(short8b*)&Bh[srow][sko]     = *(const short8b*)bhp;
      *(short8b*)&Bh[srow][sko + 8] = *(const short8b*)(bhp + 8);
      *(short8b*)&Bl[srow][sko]     = *(const short8b*)blp;
      *(short8b*)&Bl[srow][sko + 8] = *(const short8b*)(blp + 8);
    }
    __syncthreads();

    short8b ahf[4], alf[4], bhf[4], blf[4];
    #pragma unroll
    for (int mi = 0; mi < 4; ++mi) {
      ahf[mi] = *(const short8b*)&Ah[wm + mi * 16 + lr][lk];
      alf[mi] = *(const short8b*)&Al[wm + mi * 16 + lr][lk];
    }
    #pragma unroll
    for (int nj = 0; nj < 4; ++nj) {
      bhf[nj] = *(const short8b*)&Bh[wn + nj * 16 + lr][lk];
      blf[nj] = *(const short8b*)&Bl[wn + nj * 16 + lr][lk];
    }
    #pragma unroll
    for (int mi = 0; mi < 4; ++mi)
      #pragma unroll
      for (int nj = 0; nj < 4; ++nj) {
        acc[mi][nj] = __builtin_amdgcn_mfma_f32_16x16x32_bf16(
            ahf[mi], bhf[nj], acc[mi][nj], 0, 0, 0);
        acc[mi][nj] = __builtin_amdgcn_mfma_f32_16x16x32_bf16(
            ahf[mi], blf[nj], acc[mi][nj], 0, 0, 0);
        acc[mi][nj] = __builtin_amdgcn_mfma_f32_16x16x32_bf16(
            alf[mi], bhf[nj], acc[mi][nj], 0, 0, 0);
      }
  }

  if (EPI == 0) {
    // planes: [0]=Qh [1]=Ql [2]=Kh [3]=Kl [4]=Vth [5]=Vtl
    const int t = n0 / Cc;                       // 0,1,2 uniform per block
    unsigned short* Hp = planes + (size_t)(2 * t) * PLANE;
    unsigned short* Lp = planes + (size_t)(2 * t + 1) * PLANE;
    #pragma unroll
    for (int mi = 0; mi < 4; ++mi) {
      const int mbase = m0 + wm + mi * 16 + (lane >> 4) * 4;
      const int bI = mbase >> 10;
      const int nI0 = mbase & 1023;
      #pragma unroll
      for (int nj = 0; nj < 4; ++nj) {
        const int n = n0 + wn + nj * 16 + lr;
        const int rem = n - t * Cc;
        const int hh = rem >> 6, d = rem & 63;
        const size_t bhI = (size_t)(bI * Hh + hh);
        unsigned short vh4[4], vl4[4];
        #pragma unroll
        for (int r = 0; r < 4; ++r) {
          float v = acc[mi][nj][r];
          vh4[r] = bf16_hi(v);
          vl4[r] = bf16_hi(v - bf16_to_f32(vh4[r]));
        }
        if (t < 2) {
          #pragma unroll
          for (int r = 0; r < 4; ++r) {
            size_t idx = (bhI * Nn + nI0 + r) * Dd + d;
            Hp[idx] = vh4[r];
            Lp[idx] = vl4[r];
          }
        } else {
          u16x4 ph, pl;
          #pragma unroll
          for (int r = 0; r < 4; ++r) { ph[r] = vh4[r]; pl[r] = vl4[r]; }
          size_t idx = (bhI * Dd + d) * Nn + nI0;    // [bh][d][kv]
          *(u16x4*)&Hp[idx] = ph;
          *(u16x4*)&Lp[idx] = pl;
        }
      }
    }
  } else {
    #pragma unroll
    for (int mi = 0; mi < 4; ++mi) {
      #pragma unroll
      for (int nj = 0; nj < 4; ++nj) {
        #pragma unroll
        for (int r = 0; r < 4; ++r) {
          int m = m0 + wm + mi * 16 + (lane >> 4) * 4 + r;
          int n = n0 + wn + nj * 16 + lr;
          Cout[(size_t)m * Cc + n] = acc[mi][nj][r] + bias[n];
        }
      }
    }
  }
}

// ---------------------------------------------------------------------------
// attn_mfma v2: all inputs pre-split bf16 planes; staging is pure copy.
// Q frags direct from global; K tile staged to LDS (aliased by P after QK^T);
// V^T staged to LDS from the pre-transposed plane. Split-bf16 3-term MFMA.
// LDS = 4 planes x [64][72] u16 = 36.9 KB -> 4 blocks/CU.
// ---------------------------------------------------------------------------
__global__ __launch_bounds__(256)
void attn_mfma(const unsigned short* __restrict__ planes, float* __restrict__ aout) {
  constexpr int LDH2 = 72;
  __shared__ unsigned short KPh[64][LDH2], KPl[64][LDH2];   // K tile, then P
  __shared__ unsigned short Vth[64][LDH2], Vtl[64][LDH2];

  const unsigned short* Qh_p = planes;
  const unsigned short* Ql_p = planes + PLANE;
  const unsigned short* Kh_p = planes + 2 * PLANE;
  const unsigned short* Kl_p = planes + 3 * PLANE;
  const unsigned short* Vth_p = planes + 4 * PLANE;
  const unsigned short* Vtl_p = planes + 5 * PLANE;

  const int bid = blockIdx.x;           // 0..1535
  const int bh = bid >> 4, qt = bid & 15;
  const int b = bh / Hh, h = bh % Hh;
  const int tid = threadIdx.x;
  const int lane = tid & 63;
  const int wv = tid >> 6;              // 0..3
  const int q0 = wv * 16;
  const int qp = lane & 15;
  const int g  = lane >> 4;

  const int srow = tid >> 2;            // 0..63 staging row
  const int sc16 = (tid & 3) * 16;      // 0,16,32,48

  const float scale = 0.125f;

  // ---- Q fragments direct from global (once) ----
  const size_t qoff = ((size_t)bh * Nn + qt * 64 + q0 + qp) * Dd;
  short8b qfh[2], qfl[2];
  #pragma unroll
  for (int ks = 0; ks < 2; ++ks) {
    qfh[ks] = *(const short8b*)&Qh_p[qoff + ks * 32 + g * 8];
    qfl[ks] = *(const short8b*)&Ql_p[qoff + ks * 32 + g * 8];
  }

  f32x4 acc_o[4];
  #pragma unroll
  for (int dt = 0; dt < 4; ++dt) acc_o[dt] = (f32x4)0.f;
  float mrun = -1e30f, lrun = 0.f;

  for (int kt = 0; kt < 16; ++kt) {
    __syncthreads();                    // prev tile's P/V readers done
    // ---- stage K tile (pure copy) ----
    {
      const unsigned short* kh = &Kh_p[((size_t)bh * Nn + kt * 64 + srow) * Dd + sc16];
      const unsigned short* kl = &Kl_p[((size_t)bh * Nn + kt * 64 + srow) * Dd + sc16];
      *(short8b*)&KPh[srow][sc16]     = *(const short8b*)kh;
      *(short8b*)&KPh[srow][sc16 + 8] = *(const short8b*)(kh + 8);
      *(short8b*)&KPl[srow][sc16]     = *(const short8b*)kl;
      *(short8b*)&KPl[srow][sc16 + 8] = *(const short8b*)(kl + 8);
    }
    // ---- stage V^T tile (pure copy from pre-transposed plane) ----
    {
      const unsigned short* vh = &Vth_p[((size_t)bh * Dd + srow) * Nn + kt * 64 + sc16];
      const unsigned short* vl = &Vtl_p[((size_t)bh * Dd + srow) * Nn + kt * 64 + sc16];
      *(short8b*)&Vth[srow][sc16]     = *(const short8b*)vh;
      *(short8b*)&Vth[srow][sc16 + 8] = *(const short8b*)(vh + 8);
      *(short8b*)&Vtl[srow][sc16]     = *(const short8b*)vl;
      *(short8b*)&Vtl[srow][sc16 + 8] = *(const short8b*)(vl + 8);
    }
    __syncthreads();

    // ---- S^T = K·Q^T ----
    f32x4 sacc[4];
    #pragma unroll
    for (int kb = 0; kb < 4; ++kb) sacc[kb] = (f32x4)0.f;
    #pragma unroll
    for (int kb = 0; kb < 4; ++kb) {
      #pragma unroll
      for (int ks = 0; ks < 2; ++ks) {
        short8b kfh = *(const short8b*)&KPh[kb * 16 + qp][ks * 32 + g * 8];
        short8b kfl = *(const short8b*)&KPl[kb * 16 + qp][ks * 32 + g * 8];
        sacc[kb] = __builtin_amdgcn_mfma_f32_16x16x32_bf16(kfh, qfh[ks], sacc[kb], 0, 0, 0);
        sacc[kb] = __builtin_amdgcn_mfma_f32_16x16x32_bf16(kfh, qfl[ks], sacc[kb], 0, 0, 0);
        sacc[kb] = __builtin_amdgcn_mfma_f32_16x16x32_bf16(kfl, qfh[ks], sacc[kb], 0, 0, 0);
      }
    }

    // ---- online softmax (lane state keyed to q = q0+qp) ----
    float sv[16];
    #pragma unroll
    for (int kb = 0; kb < 4; ++kb)
      #pragma unroll
      for (int r = 0; r < 4; ++r) sv[kb * 4 + r] = sacc[kb][r] * scale;
    float tmax = sv[0];
    #pragma unroll
    for (int i = 1; i < 16; ++i) tmax = fmaxf(tmax, sv[i]);
    tmax = fmaxf(tmax, __shfl_xor(tmax, 16));
    tmax = fmaxf(tmax, __shfl_xor(tmax, 32));
    float mn = fmaxf(mrun, tmax);
    float corr = __expf(mrun - mn);
    float pv[16];
    float psum = 0.f;
    #pragma unroll
    for (int i = 0; i < 16; ++i) { pv[i] = __expf(sv[i] - mn); psum += pv[i]; }
    psum += __shfl_xor(psum, 16);
    psum += __shfl_xor(psum, 32);
    lrun = lrun * corr + psum;
    mrun = mn;
    #pragma unroll
    for (int r = 0; r < 4; ++r) {
      float cr = __shfl(corr, g * 4 + r);
      #pragma unroll
      for (int dt = 0; dt < 4; ++dt) acc_o[dt][r] *= cr;
    }

    __syncthreads();                    // all waves done reading K (P aliases it)
    // ---- P -> KPh/KPl (hi/lo, u32-packed) ----
    #pragma unroll
    for (int kb = 0; kb < 4; ++kb) {
      unsigned short ph[4], plo[4];
      #pragma unroll
      for (int r = 0; r < 4; ++r) {
        ph[r] = bf16_hi(pv[kb * 4 + r]);
        plo[r] = bf16_hi(pv[kb * 4 + r] - bf16_to_f32(ph[r]));
      }
      int base = kb * 16 + g * 4;
      *(unsigned int*)&KPh[q0 + qp][base]     = (unsigned)ph[0] | ((unsigned)ph[1] << 16);
      *(unsigned int*)&KPh[q0 + qp][base + 2] = (unsigned)ph[2] | ((unsigned)ph[3] << 16);
      *(unsigned int*)&KPl[q0 + qp][base]     = (unsigned)plo[0] | ((unsigned)plo[1] << 16);
      *(unsigned int*)&KPl[q0 + qp][base + 2] = (unsigned)plo[2] | ((unsigned)plo[3] << 16);
    }
    __syncthreads();

    // ---- O += P·V ----
    short8b pfh[2], pfl[2];
    #pragma unroll
    for (int ks = 0; ks < 2; ++ks) {
      pfh[ks] = *(const short8b*)&KPh[q0 + qp][ks * 32 + g * 8];
      pfl[ks] = *(const short8b*)&KPl[q0 + qp][ks * 32 + g * 8];
    }
    #pragma unroll
    for (int dt = 0; dt < 4; ++dt) {
      #pragma unroll
      for (int ks = 0; ks < 2; ++ks) {
        short8b vfh = *(const short8b*)&Vth[dt * 16 + qp][ks * 32 + g * 8];
        short8b vfl = *(const short8b*)&Vtl[dt * 16 + qp][ks * 32 + g * 8];
        acc_o[dt] = __builtin_amdgcn_mfma_f32_16x16x32_bf16(pfh[ks], vfh, acc_o[dt], 0, 0, 0);
        acc_o[dt] = __builtin_amdgcn_mfma_f32_16x16x32_bf16(pfh[ks], vfl, acc_o[dt], 0, 0, 0);
        acc_o[dt] = __builtin_amdgcn_mfma_f32_16x16x32_bf16(pfl[ks], vfh, acc_o[dt], 0, 0, 0);
      }
    }
  }

  // ---- epilogue ----
  float linv = 1.0f / lrun;
  #pragma unroll
  for (int r = 0; r < 4; ++r) {
    float lr = __shfl(linv, g * 4 + r);
    int q = qt * 64 + q0 + 4 * g + r;
    #pragma unroll
    for (int dt = 0; dt < 4; ++dt) {
      aout[((size_t)(b * Nn + q)) * Cc + h * 64 + dt * 16 + qp] = acc_o[dt][r] * lr;
    }
  }
}

// ---------------------------------------------------------------------------
// Workspace (100,663,296 B, R9-proven aliasing):
//   region A [0, 75.5MB): 6 bf16 planes (later: wprojT at base)
//   region B [75.5MB, 100.7MB): wqkvT planes (later: aout)
// ---------------------------------------------------------------------------
extern "C" void kernel_launch(void* const* d_in, const int* in_sizes, int n_in,
                              void* d_out, int out_size, void* d_ws, size_t ws_size,
                              hipStream_t stream) {
  const float* x      = (const float*)d_in[0];
  const float* w_qkv  = (const float*)d_in[1];
  const float* w_proj = (const float*)d_in[2];
  const float* b_proj = (const float*)d_in[3];
  float* out = (float*)d_out;

  char* ws = (char*)d_ws;
  unsigned short* planes  = (unsigned short*)ws;               // 6 x 12,582,912 B
  unsigned short* wprojTh = (unsigned short*)ws;               // aliases planes (phase 4+)
  unsigned short* wprojTl = (unsigned short*)(ws + 1179648);
  unsigned short* wqkvTh  = (unsigned short*)(ws + 75497472);
  unsigned short* wqkvTl  = (unsigned short*)(ws + 79036416);
  float* aout             = (float*)(ws + 75497472);           // aliases wqkvT

  transpose_split<<<dim3(QKVN / 32, Cc / 32), 256, 0, stream>>>(w_qkv, wqkvTh, wqkvTl, Cc, QKVN);

  gemm_mfma<0><<<dim3(QKVN / 128, Mtot / 128), 256, 0, stream>>>(
      x, wqkvTh, wqkvTl, nullptr, nullptr, planes, Cc);

  attn_mfma<<<BH * (Nn / 64), 256, 0, stream>>>(planes, aout);

  transpose_split<<<dim3(Cc / 32, Cc / 32), 256, 0, stream>>>(w_proj, wprojTh, wprojTl, Cc, Cc);

  gemm_mfma<1><<<dim3(Cc / 128, Mtot / 128), 256, 0, stream>>>(
      aout, wprojTh, wprojTl, b_proj, out, nullptr, Cc);
}